// Round 1
// 1268.756 us; speedup vs baseline: 2.6214x; 2.6214x over previous
//
#include <hip/hip_runtime.h>
#include <stdint.h>

// ---- problem constants ----
#define DIMC   384
#define NHEAD  12
#define HD     32
#define NTOK   49
#define BWIN   4096
#define NROWS  (BWIN * NTOK)     // 200704 token rows
#define K3     (3 * DIMC)        // 1152

typedef __bf16    bf16x8 __attribute__((ext_vector_type(8)));
typedef _Float16  f16x8  __attribute__((ext_vector_type(8)));
typedef float     f32x4  __attribute__((ext_vector_type(4)));

static __device__ __forceinline__ ushort f2bf(float f) {
    uint32_t u = __float_as_uint(f);
    u += 0x7fffu + ((u >> 16) & 1u);      // RNE
    return (ushort)(u >> 16);
}
static __device__ __forceinline__ float bf2f(ushort s) {
    return __uint_as_float(((uint32_t)s) << 16);
}
static __device__ __forceinline__ ushort f2h(float f) {
    _Float16 h = (_Float16)f;             // v_cvt_f16_f32, RNE
    return __builtin_bit_cast(unsigned short, h);
}

// async global->LDS, 16B per lane (dest must be wave-contiguous: base + lane*16)
static __device__ __forceinline__ void async_ld16(const void* g, void* l) {
    __builtin_amdgcn_global_load_lds(
        (const __attribute__((address_space(1))) void*)g,
        (__attribute__((address_space(3))) void*)l,
        16, 0, 0);
}

// ---------------- fp32 -> bf16 convert (x4 vectorized, grid-stride) --------
__global__ void cvt_f32_bf16(const float* __restrict__ src,
                             ushort* __restrict__ dst, int n4) {
    int i = blockIdx.x * blockDim.x + threadIdx.x;
    int stride = gridDim.x * blockDim.x;
    for (; i < n4; i += stride) {
        float4 v = ((const float4*)src)[i];
        ushort4 o;
        o.x = f2bf(v.x); o.y = f2bf(v.y); o.z = f2bf(v.z); o.w = f2bf(v.w);
        ((ushort4*)dst)[i] = o;
    }
}

// ---------------- bf16 GEMM: C[m][n] = sum_k A[m][k] * Bw[n][k] + bias[n] --
// A: M x K bf16 row-major; Bw: Ncols x K bf16 row-major (i.e. B^T layout).
// 128x128 tile, BK=32, 256 threads = 4 waves in 2x2, each wave 64x64 via
// 4x4 x mfma_f32_16x16x32_bf16.  m97 structure (global_load_lds width 16).
// Columns < scale_cols get multiplied by scale_val in the epilogue (used to
// fold the attention q-scale into the QKV projection).
template <bool OUT_F32>
__global__ void __launch_bounds__(256)
gemm_bt(const ushort* __restrict__ A, const ushort* __restrict__ Bw,
        const float* __restrict__ bias, void* __restrict__ Cout,
        int M, int Ncols, int K, int scale_cols, float scale_val) {
    __shared__ ushort As[128 * 32];   // [row][k], row stride 32 elems (64B)
    __shared__ ushort Bs[128 * 32];

    const int t  = threadIdx.x;
    const int m0 = blockIdx.y * 128;
    const int n0 = blockIdx.x * 128;
    const int l  = t & 63;
    const int w  = t >> 6;
    const int wm = w & 1;            // wave row (0/1) -> 64 rows of M
    const int wn = w >> 1;           // wave col (0/1) -> 64 cols of N

    f32x4 acc[4][4] = {};

    // staging addresses: thread t loads 8 bf16 (16B); 256 threads cover 64 rows
    const int rowp = t >> 2;          // 0..63
    const int ch   = t & 3;           // 16B chunk within BK=32 row (4 chunks)
    const ushort* gA0 = A  + (size_t)(m0 + rowp) * K + ch * 8;
    const ushort* gA1 = gA0 + (size_t)64 * K;
    const ushort* gB0 = Bw + (size_t)(n0 + rowp) * K + ch * 8;
    const ushort* gB1 = gB0 + (size_t)64 * K;
    ushort* lA0 = &As[t * 8];
    ushort* lA1 = &As[2048 + t * 8];
    ushort* lB0 = &Bs[t * 8];
    ushort* lB1 = &Bs[2048 + t * 8];

    const int fr = l & 15;            // fragment row within 16
    const int kb = (l >> 4) * 8;      // fragment k-offset (quad*8)

    for (int kt = 0; kt < K; kt += 32) {
        async_ld16(gA0 + kt, lA0);
        async_ld16(gA1 + kt, lA1);
        async_ld16(gB0 + kt, lB0);
        async_ld16(gB1 + kt, lB1);
        __syncthreads();   // drains vmcnt, LDS tiles ready

        bf16x8 af[4], bfr[4];
#pragma unroll
        for (int mi = 0; mi < 4; ++mi)
            af[mi] = *(const bf16x8*)&As[(64 * wm + 16 * mi + fr) * 32 + kb];
#pragma unroll
        for (int ni = 0; ni < 4; ++ni)
            bfr[ni] = *(const bf16x8*)&Bs[(64 * wn + 16 * ni + fr) * 32 + kb];
#pragma unroll
        for (int mi = 0; mi < 4; ++mi)
#pragma unroll
            for (int ni = 0; ni < 4; ++ni)
                acc[mi][ni] = __builtin_amdgcn_mfma_f32_16x16x32_bf16(
                    af[mi], bfr[ni], acc[mi][ni], 0, 0, 0);
        __syncthreads();   // protect LDS before next stage
    }

    // epilogue: C/D layout col = lane&15, row = (lane>>4)*4 + reg
    const int colBase = n0 + 64 * wn + fr;
    const int rowBase = m0 + 64 * wm + ((l >> 4) << 2);
#pragma unroll
    for (int mi = 0; mi < 4; ++mi) {
#pragma unroll
        for (int ni = 0; ni < 4; ++ni) {
            const int col = colBase + 16 * ni;
            const float bv = bias[col];
            const float sc = (col < scale_cols) ? scale_val : 1.0f;
#pragma unroll
            for (int r = 0; r < 4; ++r) {
                const int row = rowBase + 16 * mi + r;
                const float v = (acc[mi][ni][r] + bv) * sc;
                if (OUT_F32)
                    ((float*)Cout)[(size_t)row * Ncols + col] = v;
                else
                    ((ushort*)Cout)[(size_t)row * Ncols + col] = f2bf(v);
            }
        }
    }
}

// ---------------- amat precompute: bias-gather + mask, fragment-ordered ----
// amatf[w][h][tile=mi*4+ni][lane][r] (float4 per lane per tile), 64-padded:
//   value(i=16mi+4q+r, j=16ni+p) = bias_h[i][j] + mask[w][i][j]
//   j>=49 -> -1e30 (kills padded key columns in softmax), i>=49 -> 0.
__global__ void __launch_bounds__(64)
build_amat(const float* __restrict__ mask, const float* __restrict__ bias_table,
           const int* __restrict__ rel_index, float* __restrict__ amatf) {
    const int h = blockIdx.x;           // 12
    const int w = blockIdx.y;           // 64
    const int l = threadIdx.x;
    const int q = l >> 4, p = l & 15;
    float4* outp = (float4*)(amatf + (size_t)(w * NHEAD + h) * 4096);
#pragma unroll
    for (int mi = 0; mi < 4; ++mi)
#pragma unroll
        for (int ni = 0; ni < 4; ++ni) {
            float4 v;
            float* vp = (float*)&v;
#pragma unroll
            for (int r = 0; r < 4; ++r) {
                const int i = 16 * mi + 4 * q + r;
                const int j = 16 * ni + p;
                float val;
                if (j >= NTOK)      val = -1e30f;
                else if (i >= NTOK) val = 0.0f;
                else val = bias_table[rel_index[i * NTOK + j] * NHEAD + h]
                         + mask[((size_t)w * NTOK + i) * NTOK + j];
                vp[r] = val;
            }
            outp[(mi * 4 + ni) * 64 + l] = v;
        }
}

// ---------------- MFMA attention: one wave per (window b, head h) ----------
// N padded 49->64.  S = (Q*scale)K^T via 16x mfma_16x16x32_bf16 (K=32=hd in
// ONE step, fragments loaded straight from global).  Softmax rows live across
// the 16 lanes of l&15 -> shfl_xor {1,2,4,8} reductions.  P stored fp16 into
// XOR-swizzled LDS; V staged transposed+swizzled; PV = 16x mfma f16.
// O rows land on the same lane/row mapping as S, so 1/rowsum applies
// in-register.  qkv cols: s*384 + h*32 + d.  Scale is pre-folded into q.
__global__ void __launch_bounds__(64)
attn_mfma(const ushort* __restrict__ qkv, const float* __restrict__ amatf,
          ushort* __restrict__ y) {
    const int h = blockIdx.x;
    const int b = blockIdx.y;
    const int w = b & 63;
    __shared__ __align__(16) ushort Ps[64 * 64];   // P[i][j] fp16, byte ^= (i&7)<<4
    __shared__ __align__(16) ushort Vs[32 * 64];   // V^T[d][j] fp16, byte ^= ((d>>3)&1)<<6

    const int l = threadIdx.x;
    const int q = l >> 4;
    const int p = l & 15;
    const size_t rowbase = (size_t)b * NTOK * K3;
    const int kb = q * 8;                 // fragment k-offset (8 contig elems)

    // --- Q / K fragments from global (A/B frag: lane&15 = row, 8 contig k) ---
    bf16x8 qf[4], kf[4];
#pragma unroll
    for (int mi = 0; mi < 4; ++mi) {
        const int iu = 16 * mi + p;
        const int i  = iu > 48 ? 48 : iu;                 // clamp pad rows
        qf[mi] = *(const bf16x8*)(qkv + rowbase + (size_t)i * K3 + h * HD + kb);
    }
#pragma unroll
    for (int ni = 0; ni < 4; ++ni) {
        const int ju = 16 * ni + p;
        const int j  = ju > 48 ? 48 : ju;
        kf[ni] = *(const bf16x8*)(qkv + rowbase + (size_t)j * K3 + DIMC + h * HD + kb);
    }
    // --- V chunks (row-major in regs; transposed into LDS after QK) ---
    uint4 vch[4];
#pragma unroll
    for (int it = 0; it < 4; ++it) {
        const int c  = l + it * 64;                        // 256 chunks
        const int ju = c >> 2, dc = c & 3;
        const int j  = ju > 48 ? 48 : ju;
        vch[it] = *(const uint4*)(qkv + rowbase + (size_t)j * K3 + 2 * DIMC + h * HD + dc * 8);
    }

    // --- S = Q K^T : 16 MFMAs, single K=32 step ---
    f32x4 acc[4][4] = {};
#pragma unroll
    for (int mi = 0; mi < 4; ++mi)
#pragma unroll
        for (int ni = 0; ni < 4; ++ni)
            acc[mi][ni] = __builtin_amdgcn_mfma_f32_16x16x32_bf16(
                qf[mi], kf[ni], acc[mi][ni], 0, 0, 0);

    // --- + bias + mask (fragment-ordered, coalesced float4) ---
    const float4* ap = (const float4*)(amatf + (size_t)(w * NHEAD + h) * 4096);
#pragma unroll
    for (int mi = 0; mi < 4; ++mi)
#pragma unroll
        for (int ni = 0; ni < 4; ++ni) {
            const float4 am = ap[(mi * 4 + ni) * 64 + l];
            acc[mi][ni][0] += am.x; acc[mi][ni][1] += am.y;
            acc[mi][ni][2] += am.z; acc[mi][ni][3] += am.w;
        }

    // --- row softmax (row i = 16mi + 4q + r; reduce across l&15) ---
    float inv[4][4];
#pragma unroll
    for (int mi = 0; mi < 4; ++mi) {
        float mrow[4];
#pragma unroll
        for (int r = 0; r < 4; ++r) {
            float m = fmaxf(fmaxf(acc[mi][0][r], acc[mi][1][r]),
                            fmaxf(acc[mi][2][r], acc[mi][3][r]));
            m = fmaxf(m, __shfl_xor(m, 1));
            m = fmaxf(m, __shfl_xor(m, 2));
            m = fmaxf(m, __shfl_xor(m, 4));
            m = fmaxf(m, __shfl_xor(m, 8));
            mrow[r] = m;
        }
        float rsum[4] = {0.f, 0.f, 0.f, 0.f};
#pragma unroll
        for (int ni = 0; ni < 4; ++ni)
#pragma unroll
            for (int r = 0; r < 4; ++r) {
                const float e = __expf(acc[mi][ni][r] - mrow[r]);  // pad j: exp(-1e30-m)=0
                acc[mi][ni][r] = e;
                rsum[r] += e;
            }
#pragma unroll
        for (int r = 0; r < 4; ++r) {
            float s = rsum[r];
            s += __shfl_xor(s, 1);
            s += __shfl_xor(s, 2);
            s += __shfl_xor(s, 4);
            s += __shfl_xor(s, 8);
            inv[mi][r] = __builtin_amdgcn_rcpf(s);   // normalize at epilogue
        }
    }

    // --- P -> LDS fp16 (unnormalized, <=1), xor-swizzled rows ---
#pragma unroll
    for (int mi = 0; mi < 4; ++mi)
#pragma unroll
        for (int ni = 0; ni < 4; ++ni)
#pragma unroll
            for (int r = 0; r < 4; ++r) {
                const int row = 16 * mi + 4 * q + r;
                const int off = (row * 128 + (16 * ni + p) * 2) ^ ((row & 7) << 4);
                *(ushort*)((char*)Ps + off) = f2h(acc[mi][ni][r]);
            }
    // --- V^T -> LDS fp16 ---
#pragma unroll
    for (int it = 0; it < 4; ++it) {
        const int c  = l + it * 64;
        const int ju = c >> 2, dc = c & 3;
        const ushort* vsrc = (const ushort*)&vch[it];
#pragma unroll
        for (int e = 0; e < 8; ++e) {
            const int d   = dc * 8 + e;
            const int off = (d * 128 + ju * 2) ^ (((d >> 3) & 1) << 6);
            *(ushort*)((char*)Vs + off) = f2h(bf2f(vsrc[e]));
        }
    }
    __syncthreads();

    // --- O = P V : 16 MFMAs (4 i-tiles x 2 d-tiles x 2 K-steps of j) ---
    f32x4 o[4][2] = {};
#pragma unroll
    for (int kk = 0; kk < 2; ++kk) {
        f16x8 pa[4], vb[2];
#pragma unroll
        for (int mi = 0; mi < 4; ++mi) {
            const int row = 16 * mi + p;
            const int off = (row * 128 + kk * 64 + q * 16) ^ ((row & 7) << 4);
            pa[mi] = *(const f16x8*)((const char*)Ps + off);
        }
#pragma unroll
        for (int ni = 0; ni < 2; ++ni) {
            const int d   = 16 * ni + p;
            const int off = (d * 128 + kk * 64 + q * 16) ^ (((d >> 3) & 1) << 6);
            vb[ni] = *(const f16x8*)((const char*)Vs + off);
        }
#pragma unroll
        for (int mi = 0; mi < 4; ++mi)
#pragma unroll
            for (int ni = 0; ni < 2; ++ni)
                o[mi][ni] = __builtin_amdgcn_mfma_f32_16x16x32_f16(
                    pa[mi], vb[ni], o[mi][ni], 0, 0, 0);
    }

    // --- normalize + store (O rows share S's lane/row mapping) ---
    ushort* yb = y + (size_t)b * NTOK * DIMC + h * HD;
#pragma unroll
    for (int mi = 0; mi < 4; ++mi)
#pragma unroll
        for (int r = 0; r < 4; ++r) {
            const int i = 16 * mi + 4 * q + r;
            if (i < NTOK) {
                const float s = inv[mi][r];
                yb[(size_t)i * DIMC + p]      = f2bf(o[mi][0][r] * s);
                yb[(size_t)i * DIMC + 16 + p] = f2bf(o[mi][1][r] * s);
            }
        }
}

// ---------------- launch ----------------
extern "C" void kernel_launch(void* const* d_in, const int* in_sizes, int n_in,
                              void* d_out, int out_size, void* d_ws, size_t ws_size,
                              hipStream_t stream) {
    const float* x          = (const float*)d_in[0];
    const float* mask       = (const float*)d_in[1];
    const float* qkv_w      = (const float*)d_in[2];
    const float* qkv_b      = (const float*)d_in[3];
    const float* proj_w     = (const float*)d_in[4];
    const float* proj_b     = (const float*)d_in[5];
    const float* bias_table = (const float*)d_in[6];
    const int*   rel_index  = (const int*)d_in[7];

    // workspace layout (ushort elements)
    ushort* ws   = (ushort*)d_ws;
    ushort* xb   = ws;                                   // 77,070,336  (x bf16; reused as y)
    ushort* wqkv = ws + (size_t)77070336;                // 442,368
    ushort* wprj = ws + (size_t)77070336 + 442368;       // 147,456
    ushort* qkvb = ws + (size_t)77070336 + 442368 + 147456; // 231,211,008
    float*  amat = (float*)(ws + (size_t)308871168);     // 3,145,728 floats (12.6 MB)
    // total ws requirement: ~630.3 MB

    // 1) converts + bias/mask fragment table
    cvt_f32_bf16<<<4096, 256, 0, stream>>>(x, xb, (NROWS * DIMC) / 4);
    cvt_f32_bf16<<<432, 256, 0, stream>>>(qkv_w, wqkv, (K3 * DIMC) / 4);
    cvt_f32_bf16<<<144, 256, 0, stream>>>(proj_w, wprj, (DIMC * DIMC) / 4);
    build_amat<<<dim3(NHEAD, 64), 64, 0, stream>>>(mask, bias_table, rel_index, amat);

    // 2) QKV GEMM: (200704x384) @ (1152x384)^T -> qkv bf16, q-cols pre-scaled
    gemm_bt<false><<<dim3(K3 / 128, NROWS / 128), 256, 0, stream>>>(
        xb, wqkv, qkv_b, qkvb, NROWS, K3, DIMC, DIMC, 0.17677669529663687f);

    // 3) MFMA attention -> y (bf16, aliases xb)
    attn_mfma<<<dim3(NHEAD, BWIN), 64, 0, stream>>>(qkvb, amat, xb);

    // 4) proj GEMM: (200704x384) @ (384x384)^T -> d_out fp32
    gemm_bt<true><<<dim3(DIMC / 128, NROWS / 128), 256, 0, stream>>>(
        xb, wprj, proj_b, d_out, NROWS, DIMC, DIMC, 0, 1.0f);
}

// Round 2
// 1186.995 us; speedup vs baseline: 2.8020x; 1.0689x over previous
//
#include <hip/hip_runtime.h>
#include <stdint.h>

// ---- problem constants ----
#define DIMC   384
#define NHEAD  12
#define HD     32
#define NTOK   49
#define BWIN   4096
#define NROWS  (BWIN * NTOK)     // 200704 token rows
#define K3     (3 * DIMC)        // 1152

typedef __bf16    bf16x8 __attribute__((ext_vector_type(8)));
typedef _Float16  f16x8  __attribute__((ext_vector_type(8)));
typedef float     f32x4  __attribute__((ext_vector_type(4)));

static __device__ __forceinline__ ushort f2bf(float f) {
    uint32_t u = __float_as_uint(f);
    u += 0x7fffu + ((u >> 16) & 1u);      // RNE
    return (ushort)(u >> 16);
}
static __device__ __forceinline__ float bf2f(ushort s) {
    return __uint_as_float(((uint32_t)s) << 16);
}
static __device__ __forceinline__ ushort f2h(float f) {
    _Float16 h = (_Float16)f;             // v_cvt_f16_f32, RNE
    return __builtin_bit_cast(unsigned short, h);
}

// async global->LDS, 16B per lane (dest must be wave-contiguous: base + lane*16)
static __device__ __forceinline__ void async_ld16(const void* g, void* l) {
    __builtin_amdgcn_global_load_lds(
        (const __attribute__((address_space(1))) void*)g,
        (__attribute__((address_space(3))) void*)l,
        16, 0, 0);
}

// ---------------- fp32 -> bf16 convert (x4 vectorized, grid-stride) --------
__global__ void cvt_f32_bf16(const float* __restrict__ src,
                             ushort* __restrict__ dst, int n4) {
    int i = blockIdx.x * blockDim.x + threadIdx.x;
    int stride = gridDim.x * blockDim.x;
    for (; i < n4; i += stride) {
        float4 v = ((const float4*)src)[i];
        ushort4 o;
        o.x = f2bf(v.x); o.y = f2bf(v.y); o.z = f2bf(v.z); o.w = f2bf(v.w);
        ((ushort4*)dst)[i] = o;
    }
}

// ---------------- bf16 GEMM: C[m][n] = sum_k A[m][k] * Bw[n][k] + bias[n] --
// A: M x K bf16 row-major; Bw: Ncols x K bf16 row-major (i.e. B^T layout).
// 128x128 tile, BK=64 (two concatenated 32-K sub-tiles: ONE stage+barrier
// pair per 64-K), 256 threads = 4 waves in 2x2, each wave 64x64 via 4x4 x
// mfma_f32_16x16x32_bf16.  1D grid with bijective XCD-chunk swizzle so the
// nbx blocks sharing an A-panel land on the SAME XCD (A fetched once/L2).
// Requires gridDim.x % 8 == 0 and K % 64 == 0.
template <bool OUT_F32>
__global__ void __launch_bounds__(256)
gemm_bt(const ushort* __restrict__ A, const ushort* __restrict__ Bw,
        const float* __restrict__ bias, void* __restrict__ Cout,
        int M, int Ncols, int K, int scale_cols, float scale_val) {
    __shared__ ushort As[128 * 64];   // two [128][32] sub-tiles (s=0 | s=1)
    __shared__ ushort Bs[128 * 64];

    const int t = threadIdx.x;
    // XCD-chunk swizzle: consecutive work-ids within one XCD's chunk walk
    // bx fastest -> A-panel reuse stays in that XCD's L2.
    const int nwg   = gridDim.x;
    const int chunk = nwg >> 3;
    const int b0    = blockIdx.x;
    const int swz   = (b0 & 7) * chunk + (b0 >> 3);
    const int nbx   = Ncols >> 7;
    const int bx    = swz % nbx;
    const int by    = swz / nbx;
    const int m0 = by * 128;
    const int n0 = bx * 128;

    const int l  = t & 63;
    const int w  = t >> 6;
    const int wm = w & 1;            // wave row (0/1) -> 64 rows of M
    const int wn = w >> 1;           // wave col (0/1) -> 64 cols of N

    f32x4 acc[4][4] = {};

    // staging: thread t owns row rw=t>>2 (0..63), 16B chunk kc4=t&3 of a
    // 32-elem k-half.  4 rounds per matrix: {rows 0-63,s0},{64-127,s0},
    // {0-63,s1},{64-127,s1} -> LDS stays linear (dest = base + t*16B).
    const int rw  = t >> 2;
    const int kc4 = t & 3;
    const ushort* gA = A  + (size_t)(m0 + rw) * K + kc4 * 8;
    const ushort* gB = Bw + (size_t)(n0 + rw) * K + kc4 * 8;
    const size_t rstep = (size_t)64 * K;     // +64 rows
    ushort* lA = &As[t * 8];
    ushort* lB = &Bs[t * 8];

    const int fr = l & 15;            // fragment row within 16
    const int kb = (l >> 4) * 8;      // fragment k-offset (quad*8)

    for (int kt = 0; kt < K; kt += 64) {
        async_ld16(gA + kt,             lA);
        async_ld16(gA + kt + rstep,     lA + 2048);
        async_ld16(gA + kt + 32,        lA + 4096);
        async_ld16(gA + kt + 32 + rstep,lA + 6144);
        async_ld16(gB + kt,             lB);
        async_ld16(gB + kt + rstep,     lB + 2048);
        async_ld16(gB + kt + 32,        lB + 4096);
        async_ld16(gB + kt + 32 + rstep,lB + 6144);
        __syncthreads();   // drains vmcnt, both 32-K sub-tiles ready

#pragma unroll
        for (int s = 0; s < 2; ++s) {
            bf16x8 af[4], bfr[4];
#pragma unroll
            for (int mi = 0; mi < 4; ++mi)
                af[mi] = *(const bf16x8*)&As[s * 4096 + (64 * wm + 16 * mi + fr) * 32 + kb];
#pragma unroll
            for (int ni = 0; ni < 4; ++ni)
                bfr[ni] = *(const bf16x8*)&Bs[s * 4096 + (64 * wn + 16 * ni + fr) * 32 + kb];
#pragma unroll
            for (int mi = 0; mi < 4; ++mi)
#pragma unroll
                for (int ni = 0; ni < 4; ++ni)
                    acc[mi][ni] = __builtin_amdgcn_mfma_f32_16x16x32_bf16(
                        af[mi], bfr[ni], acc[mi][ni], 0, 0, 0);
        }
        __syncthreads();   // protect LDS before next stage
    }

    // epilogue: C/D layout col = lane&15, row = (lane>>4)*4 + reg
    const int colBase = n0 + 64 * wn + fr;
    const int rowBase = m0 + 64 * wm + ((l >> 4) << 2);
#pragma unroll
    for (int mi = 0; mi < 4; ++mi) {
#pragma unroll
        for (int ni = 0; ni < 4; ++ni) {
            const int col = colBase + 16 * ni;
            const float bv = bias[col];
            const float sc = (col < scale_cols) ? scale_val : 1.0f;
#pragma unroll
            for (int r = 0; r < 4; ++r) {
                const int row = rowBase + 16 * mi + r;
                const float v = (acc[mi][ni][r] + bv) * sc;
                if (OUT_F32)
                    ((float*)Cout)[(size_t)row * Ncols + col] = v;
                else
                    ((ushort*)Cout)[(size_t)row * Ncols + col] = f2bf(v);
            }
        }
    }
}

// ---------------- amat precompute: bias-gather + mask, fragment-ordered ----
// amatf[w][h][tile=mi*4+ni][lane][r] (float4 per lane per tile), 64-padded:
//   value(i=16mi+4q+r, j=16ni+p) = bias_h[i][j] + mask[w][i][j]
//   j>=49 -> -1e30 (kills padded key columns in softmax), i>=49 -> 0.
__global__ void __launch_bounds__(64)
build_amat(const float* __restrict__ mask, const float* __restrict__ bias_table,
           const int* __restrict__ rel_index, float* __restrict__ amatf) {
    const int h = blockIdx.x;           // 12
    const int w = blockIdx.y;           // 64
    const int l = threadIdx.x;
    const int q = l >> 4, p = l & 15;
    float4* outp = (float4*)(amatf + (size_t)(w * NHEAD + h) * 4096);
#pragma unroll
    for (int mi = 0; mi < 4; ++mi)
#pragma unroll
        for (int ni = 0; ni < 4; ++ni) {
            float4 v;
            float* vp = (float*)&v;
#pragma unroll
            for (int r = 0; r < 4; ++r) {
                const int i = 16 * mi + 4 * q + r;
                const int j = 16 * ni + p;
                float val;
                if (j >= NTOK)      val = -1e30f;
                else if (i >= NTOK) val = 0.0f;
                else val = bias_table[rel_index[i * NTOK + j] * NHEAD + h]
                         + mask[((size_t)w * NTOK + i) * NTOK + j];
                vp[r] = val;
            }
            outp[(mi * 4 + ni) * 64 + l] = v;
        }
}

// ---------------- MFMA attention: one wave per (window b, head h) ----------
// N padded 49->64.  S = (Q*scale)K^T via 16x mfma_16x16x32_bf16 (K=32=hd in
// ONE step, fragments loaded straight from global).  Softmax rows live across
// the 16 lanes of l&15 -> shfl_xor {1,2,4,8} reductions.  P stored fp16 into
// XOR-swizzled LDS; V staged transposed+swizzled; PV = 16x mfma f16.
// O rows land on the same lane/row mapping as S, so 1/rowsum applies
// in-register.  qkv cols: s*384 + h*32 + d.  Scale is pre-folded into q.
__global__ void __launch_bounds__(64)
attn_mfma(const ushort* __restrict__ qkv, const float* __restrict__ amatf,
          ushort* __restrict__ y) {
    const int h = blockIdx.x;
    const int b = blockIdx.y;
    const int w = b & 63;
    __shared__ __align__(16) ushort Ps[64 * 64];   // P[i][j] fp16, byte ^= (i&7)<<4
    __shared__ __align__(16) ushort Vs[32 * 64];   // V^T[d][j] fp16, byte ^= ((d>>3)&1)<<6

    const int l = threadIdx.x;
    const int q = l >> 4;
    const int p = l & 15;
    const size_t rowbase = (size_t)b * NTOK * K3;
    const int kb = q * 8;                 // fragment k-offset (8 contig elems)

    // --- Q / K fragments from global (A/B frag: lane&15 = row, 8 contig k) ---
    bf16x8 qf[4], kf[4];
#pragma unroll
    for (int mi = 0; mi < 4; ++mi) {
        const int iu = 16 * mi + p;
        const int i  = iu > 48 ? 48 : iu;                 // clamp pad rows
        qf[mi] = *(const bf16x8*)(qkv + rowbase + (size_t)i * K3 + h * HD + kb);
    }
#pragma unroll
    for (int ni = 0; ni < 4; ++ni) {
        const int ju = 16 * ni + p;
        const int j  = ju > 48 ? 48 : ju;
        kf[ni] = *(const bf16x8*)(qkv + rowbase + (size_t)j * K3 + DIMC + h * HD + kb);
    }
    // --- V chunks (row-major in regs; transposed into LDS after QK) ---
    uint4 vch[4];
#pragma unroll
    for (int it = 0; it < 4; ++it) {
        const int c  = l + it * 64;                        // 256 chunks
        const int ju = c >> 2, dc = c & 3;
        const int j  = ju > 48 ? 48 : ju;
        vch[it] = *(const uint4*)(qkv + rowbase + (size_t)j * K3 + 2 * DIMC + h * HD + dc * 8);
    }

    // --- S = Q K^T : 16 MFMAs, single K=32 step ---
    f32x4 acc[4][4] = {};
#pragma unroll
    for (int mi = 0; mi < 4; ++mi)
#pragma unroll
        for (int ni = 0; ni < 4; ++ni)
            acc[mi][ni] = __builtin_amdgcn_mfma_f32_16x16x32_bf16(
                qf[mi], kf[ni], acc[mi][ni], 0, 0, 0);

    // --- + bias + mask (fragment-ordered, coalesced float4) ---
    const float4* ap = (const float4*)(amatf + (size_t)(w * NHEAD + h) * 4096);
#pragma unroll
    for (int mi = 0; mi < 4; ++mi)
#pragma unroll
        for (int ni = 0; ni < 4; ++ni) {
            const float4 am = ap[(mi * 4 + ni) * 64 + l];
            acc[mi][ni][0] += am.x; acc[mi][ni][1] += am.y;
            acc[mi][ni][2] += am.z; acc[mi][ni][3] += am.w;
        }

    // --- row softmax (row i = 16mi + 4q + r; reduce across l&15) ---
    float inv[4][4];
#pragma unroll
    for (int mi = 0; mi < 4; ++mi) {
        float mrow[4];
#pragma unroll
        for (int r = 0; r < 4; ++r) {
            float m = fmaxf(fmaxf(acc[mi][0][r], acc[mi][1][r]),
                            fmaxf(acc[mi][2][r], acc[mi][3][r]));
            m = fmaxf(m, __shfl_xor(m, 1));
            m = fmaxf(m, __shfl_xor(m, 2));
            m = fmaxf(m, __shfl_xor(m, 4));
            m = fmaxf(m, __shfl_xor(m, 8));
            mrow[r] = m;
        }
        float rsum[4] = {0.f, 0.f, 0.f, 0.f};
#pragma unroll
        for (int ni = 0; ni < 4; ++ni)
#pragma unroll
            for (int r = 0; r < 4; ++r) {
                const float e = __expf(acc[mi][ni][r] - mrow[r]);  // pad j: exp(-1e30-m)=0
                acc[mi][ni][r] = e;
                rsum[r] += e;
            }
#pragma unroll
        for (int r = 0; r < 4; ++r) {
            float s = rsum[r];
            s += __shfl_xor(s, 1);
            s += __shfl_xor(s, 2);
            s += __shfl_xor(s, 4);
            s += __shfl_xor(s, 8);
            inv[mi][r] = __builtin_amdgcn_rcpf(s);   // normalize at epilogue
        }
    }

    // --- P -> LDS fp16 (unnormalized, <=1), xor-swizzled rows ---
#pragma unroll
    for (int mi = 0; mi < 4; ++mi)
#pragma unroll
        for (int ni = 0; ni < 4; ++ni)
#pragma unroll
            for (int r = 0; r < 4; ++r) {
                const int row = 16 * mi + 4 * q + r;
                const int off = (row * 128 + (16 * ni + p) * 2) ^ ((row & 7) << 4);
                *(ushort*)((char*)Ps + off) = f2h(acc[mi][ni][r]);
            }
    // --- V^T -> LDS fp16 ---
#pragma unroll
    for (int it = 0; it < 4; ++it) {
        const int c  = l + it * 64;
        const int ju = c >> 2, dc = c & 3;
        const ushort* vsrc = (const ushort*)&vch[it];
#pragma unroll
        for (int e = 0; e < 8; ++e) {
            const int d   = dc * 8 + e;
            const int off = (d * 128 + ju * 2) ^ (((d >> 3) & 1) << 6);
            *(ushort*)((char*)Vs + off) = f2h(bf2f(vsrc[e]));
        }
    }
    __syncthreads();

    // --- O = P V : 16 MFMAs (4 i-tiles x 2 d-tiles x 2 K-steps of j) ---
    f32x4 o[4][2] = {};
#pragma unroll
    for (int kk = 0; kk < 2; ++kk) {
        f16x8 pa[4], vb[2];
#pragma unroll
        for (int mi = 0; mi < 4; ++mi) {
            const int row = 16 * mi + p;
            const int off = (row * 128 + kk * 64 + q * 16) ^ ((row & 7) << 4);
            pa[mi] = *(const f16x8*)((const char*)Ps + off);
        }
#pragma unroll
        for (int ni = 0; ni < 2; ++ni) {
            const int d   = 16 * ni + p;
            const int off = (d * 128 + kk * 64 + q * 16) ^ (((d >> 3) & 1) << 6);
            vb[ni] = *(const f16x8*)((const char*)Vs + off);
        }
#pragma unroll
        for (int mi = 0; mi < 4; ++mi)
#pragma unroll
            for (int ni = 0; ni < 2; ++ni)
                o[mi][ni] = __builtin_amdgcn_mfma_f32_16x16x32_f16(
                    pa[mi], vb[ni], o[mi][ni], 0, 0, 0);
    }

    // --- normalize + store (O rows share S's lane/row mapping) ---
    ushort* yb = y + (size_t)b * NTOK * DIMC + h * HD;
#pragma unroll
    for (int mi = 0; mi < 4; ++mi)
#pragma unroll
        for (int r = 0; r < 4; ++r) {
            const int i = 16 * mi + 4 * q + r;
            if (i < NTOK) {
                const float s = inv[mi][r];
                yb[(size_t)i * DIMC + p]      = f2bf(o[mi][0][r] * s);
                yb[(size_t)i * DIMC + 16 + p] = f2bf(o[mi][1][r] * s);
            }
        }
}

// ---------------- launch ----------------
extern "C" void kernel_launch(void* const* d_in, const int* in_sizes, int n_in,
                              void* d_out, int out_size, void* d_ws, size_t ws_size,
                              hipStream_t stream) {
    const float* x          = (const float*)d_in[0];
    const float* mask       = (const float*)d_in[1];
    const float* qkv_w      = (const float*)d_in[2];
    const float* qkv_b      = (const float*)d_in[3];
    const float* proj_w     = (const float*)d_in[4];
    const float* proj_b     = (const float*)d_in[5];
    const float* bias_table = (const float*)d_in[6];
    const int*   rel_index  = (const int*)d_in[7];

    // workspace layout (ushort elements)
    ushort* ws   = (ushort*)d_ws;
    ushort* xb   = ws;                                   // 77,070,336  (x bf16; reused as y)
    ushort* wqkv = ws + (size_t)77070336;                // 442,368
    ushort* wprj = ws + (size_t)77070336 + 442368;       // 147,456
    ushort* qkvb = ws + (size_t)77070336 + 442368 + 147456; // 231,211,008
    float*  amat = (float*)(ws + (size_t)308871168);     // 3,145,728 floats (12.6 MB)
    // total ws requirement: ~630.3 MB

    // 1) converts + bias/mask fragment table
    cvt_f32_bf16<<<4096, 256, 0, stream>>>(x, xb, (NROWS * DIMC) / 4);
    cvt_f32_bf16<<<432, 256, 0, stream>>>(qkv_w, wqkv, (K3 * DIMC) / 4);
    cvt_f32_bf16<<<144, 256, 0, stream>>>(proj_w, wprj, (DIMC * DIMC) / 4);
    build_amat<<<dim3(NHEAD, 64), 64, 0, stream>>>(mask, bias_table, rel_index, amat);

    // 2) QKV GEMM: (200704x384) @ (1152x384)^T -> qkv bf16, q-cols pre-scaled
    //    1D grid 9*1568 = 14112 (div by 8 for XCD swizzle)
    gemm_bt<false><<<(K3 / 128) * (NROWS / 128), 256, 0, stream>>>(
        xb, wqkv, qkv_b, qkvb, NROWS, K3, DIMC, DIMC, 0.17677669529663687f);

    // 3) MFMA attention -> y (bf16, aliases xb)
    attn_mfma<<<dim3(NHEAD, BWIN), 64, 0, stream>>>(qkvb, amat, xb);

    // 4) proj GEMM: (200704x384) @ (384x384)^T -> d_out fp32
    //    1D grid 3*1568 = 4704 (div by 8)
    gemm_bt<true><<<(DIMC / 128) * (NROWS / 128), 256, 0, stream>>>(
        xb, wprj, proj_b, d_out, NROWS, DIMC, DIMC, 0, 1.0f);
}